// Round 7
// baseline (273.999 us; speedup 1.0000x reference)
//
#include <hip/hip_runtime.h>
#include <math.h>

#define EPSF 1e-7f
#define Bsz 2
#define Cch 1024
#define Hh 60
#define Ssz 3600
#define HID 256
#define TDIM 300
#define MH 473

// pool tiling
#define TROWS 15
#define LROWS 21          // TROWS + 6 halo
#define LPITCH 68         // (still used by k2/k5 LDS tiles)

// workspace layout (float offsets)
// [0, 43200) zeroed by hipMemsetAsync each launch (SN2 + DOT atomic planes)
#define OFF_SN2    0               // 6*3600 sum over channels of pool^2 (atomic)
#define OFF_DOT    21600           // 6*3600 dot planes (atomic)
#define OFF_WMAP   43200           // 6*3600  mask-premultiplied pool(1/sn)
#define OFF_V      64800           // 6*1024
#define OFF_SCORE  70944           // 2*3600
#define OFF_KBAR   78144           // 2*256
#define OFF_U      78656           // 2*256

// ============ k1: pool^2 -> SN2 (512 blocks, reg-resident) + u-GEMV (2) =====
// pool: lane=column, rows in registers, vertical sums in-reg, horizontal via
// __shfl. No __syncthreads in the channel loop; LDS only for final reduce.
__global__ void __launch_bounds__(256)
k_pool_u(const float* __restrict__ supp, const float* __restrict__ masks,
         const float* __restrict__ text, const float* __restrict__ proto,
         const float* __restrict__ w_q,  const float* __restrict__ w_bl,
         const float* __restrict__ w_k,  float* __restrict__ ws) {
    __shared__ __align__(16) char smem[10816];
    int tid = threadIdx.x;
    int bid = blockIdx.x;

    if (bid >= 512) {
        // ---- u role: u = w_k^T (w_bl^T (w_q^T [text;proto])), 4-wave float4 ----
        int b = bid - 512;
        int lane = tid & 63, wv = tid >> 6;
        float4* p4  = (float4*)smem;            // [4][64]
        float*  pf  = (float*)smem;
        float*  xs  = (float*)(smem + 4096);    // 556
        float*  qxs = (float*)(smem + 6400);    // 256
        float*  qws = (float*)(smem + 7424);    // 256
        const float4* wq4  = (const float4*)w_q;
        const float4* wbl4 = (const float4*)w_bl;
        const float4* wk4  = (const float4*)w_k;

        #pragma unroll
        for (int j = 0; j < 3; ++j) {
            int e = tid + 256 * j;
            if (e < TDIM) xs[e] = text[b * TDIM + e];
            else if (e < TDIM + HID) xs[e] = proto[b * HID + e - TDIM];
        }
        __syncthreads();
        float4 acc = {0.f, 0.f, 0.f, 0.f};
        #pragma unroll 4
        for (int j = 0; j < 139; ++j) {
            int e = wv + 4 * j;
            if (e < TDIM + HID) {
                float x = xs[e];
                float4 f = wq4[(size_t)e * 64 + lane];
                acc.x += x * f.x; acc.y += x * f.y; acc.z += x * f.z; acc.w += x * f.w;
            }
        }
        p4[wv * 64 + lane] = acc;
        __syncthreads();
        qxs[tid] = pf[tid] + pf[256 + tid] + pf[512 + tid] + pf[768 + tid];
        __syncthreads();

        acc.x = acc.y = acc.z = acc.w = 0.f;
        #pragma unroll 4
        for (int j = 0; j < 64; ++j) {
            int e = wv + 4 * j;
            float x = qxs[e];
            float4 f = wbl4[(size_t)e * 64 + lane];
            acc.x += x * f.x; acc.y += x * f.y; acc.z += x * f.z; acc.w += x * f.w;
        }
        p4[wv * 64 + lane] = acc;
        __syncthreads();
        qws[tid] = pf[tid] + pf[256 + tid] + pf[512 + tid] + pf[768 + tid];
        __syncthreads();

        acc.x = acc.y = acc.z = acc.w = 0.f;
        #pragma unroll 4
        for (int j = 0; j < 64; ++j) {
            int e = wv + 4 * j;
            float x = qws[e];
            float4 f = wk4[(size_t)e * 64 + lane];
            acc.x += x * f.x; acc.y += x * f.y; acc.z += x * f.z; acc.w += x * f.w;
        }
        p4[wv * 64 + lane] = acc;
        __syncthreads();
        ws[OFF_U + b * HID + tid] = pf[tid] + pf[256 + tid] + pf[512 + tid] + pf[768 + tid];
        return;
    }

    // ---- pool role: bid = (b<<8) | (tile<<6) | chunk ----
    float* accL = (float*)smem;                 // 2700 floats
    for (int i = tid; i < 2700; i += 256) accL[i] = 0.f;
    __syncthreads();

    int lane = tid & 63, wv = tid >> 6;
    int b = bid >> 8, tile = (bid >> 6) & 3, chunk = bid & 63;
    int y0 = tile * TROWS;
    int c = lane;
    int cmin = (c < 59) ? c : 59;
    bool cok = c < 60;

    // mask column in registers (shared across all channels of this block)
    float mk[21];
    #pragma unroll
    for (int r = 0; r < 21; ++r) {
        int iy = y0 - 3 + r;
        float mv = 0.f;
        if (iy >= 0 && iy < Hh)
            mv = masks[(size_t)b * MH * MH + (size_t)(iy * 8) * MH + cmin * 8];
        mk[r] = cok ? mv : 0.f;
    }

    float acc0[15], acc1[15], acc2[15];
    #pragma unroll
    for (int rr = 0; rr < 15; ++rr) { acc0[rr] = 0.f; acc1[rr] = 0.f; acc2[rr] = 0.f; }

    int ch0 = chunk * 16 + wv * 4;
    for (int cc2 = 0; cc2 < 4; ++cc2) {
        const float* sp = supp + ((size_t)b * Cch + ch0 + cc2) * Ssz;
        float raw[21];
        #pragma unroll
        for (int r = 0; r < 21; ++r) {
            int iy = y0 - 3 + r;
            raw[r] = 0.f;
            if (iy >= 0 && iy < Hh) raw[r] = sp[iy * 60 + cmin] * mk[r];
        }
        // vertical sliding sums (center row = rr+3): v5 = raw[rr+1..rr+5], v7 = raw[rr..rr+6]
        float s5 = raw[1] + raw[2] + raw[3] + raw[4] + raw[5];
        float s7 = s5 + raw[0] + raw[6];
        #pragma unroll
        for (int rr = 0; rr < 15; ++rr) {
            float h5 = __shfl(s5, c - 2, 64) + __shfl(s5, c - 1, 64) + s5
                     + __shfl(s5, c + 1, 64) + __shfl(s5, c + 2, 64);
            float rc = raw[rr + 3];
            float h7 = __shfl(rc, c - 3, 64) + __shfl(rc, c - 2, 64) + __shfl(rc, c - 1, 64)
                     + rc
                     + __shfl(rc, c + 1, 64) + __shfl(rc, c + 2, 64) + __shfl(rc, c + 3, 64);
            float p55 = h5 * (1.f / 25.f);
            float p71 = s7 * (1.f / 7.f);
            float p17 = h7 * (1.f / 7.f);
            acc0[rr] += p55 * p55;
            acc1[rr] += p71 * p71;
            acc2[rr] += p17 * p17;
            if (rr < 14) {
                s5 += raw[rr + 6] - raw[rr + 1];
                s7 += raw[rr + 7] - raw[rr];
            }
        }
    }

    // block-level reduce: LDS atomics (4 waves -> one plane), then global atomics
    #pragma unroll
    for (int rr = 0; rr < 15; ++rr) {
        if (cok) {
            atomicAdd(&accL[0 * 900 + rr * 60 + c], acc0[rr]);
            atomicAdd(&accL[1 * 900 + rr * 60 + c], acc1[rr]);
            atomicAdd(&accL[2 * 900 + rr * 60 + c], acc2[rr]);
        }
    }
    __syncthreads();
    float* gacc = ws + OFF_SN2 + (size_t)(b * 3) * Ssz;
    for (int i = tid; i < 2700; i += 256) {
        int t = i / 900, rem = i - t * 900;
        int rr = rem / 60, x = rem - rr * 60;
        atomicAdd(&gacc[(size_t)t * Ssz + (y0 + rr) * 60 + x], accL[i]);
    }
}

// ============ k2: wmap (24 blocks) + score strips (58 blocks) ===============
__global__ void __launch_bounds__(1024)
k_wmap_score(const float* __restrict__ masks, const float* __restrict__ kin,
             float* __restrict__ ws) {
    int bid = blockIdx.x;
    int tid = threadIdx.x;

    if (bid < 24) {
        // ---- wmap role ----
        __shared__ float inv[LROWS * LPITCH];
        int tile = bid & 3, bk = bid >> 2;
        int b = bk / 3, kt = bk % 3;
        int y0 = tile * TROWS;
        for (int i = tid; i < LROWS * LPITCH; i += 1024) inv[i] = 0.f;
        __syncthreads();
        const float* pp = ws + OFF_SN2 + (size_t)bk * Ssz;
        #pragma unroll
        for (int j = 0; j < 2; ++j) {
            int idx = tid + 1024 * j;
            if (idx < 1260) {
                int r = idx / 60, x = idx - 60 * r;
                int iy = y0 - 3 + r;
                if (iy >= 0 && iy < Hh)
                    inv[r * LPITCH + 4 + x] = 1.0f / sqrtf(fmaxf(pp[iy * 60 + x], 1e-30f));
            }
        }
        __syncthreads();
        int kh = (kt == 0) ? 5 : (kt == 1) ? 7 : 1;
        int kw = (kt == 0) ? 5 : (kt == 2) ? 7 : 1;
        int rh = kh / 2, rw = kw / 2;
        float norm = 1.f / (float)(kh * kw);
        int o = tid;
        if (o < 900) {
            int oy = o / 60, x = o - 60 * oy;
            int base = (oy + 3) * LPITCH + 4 + x;
            float s = 0.f;
            for (int dy = -rh; dy <= rh; ++dy)
                for (int dx = -rw; dx <= rw; ++dx)
                    s += inv[base + dy * LPITCH + dx];
            int gy = y0 + oy;
            float m = masks[(size_t)b * MH * MH + (size_t)(gy * 8) * MH + x * 8];
            ws[OFF_WMAP + (size_t)bk * Ssz + gy * 60 + x] = s * norm * m;
        }
        return;
    }

    // ---- score role: 128 s-values, 8-way i-split, LDS reduce ----
    __shared__ float us[HID];
    __shared__ float part[8][128];
    int idx = bid - 24;            // 0..57
    int st = idx % 29, b = idx / 29;
    if (tid < HID) us[tid] = ws[OFF_U + b * HID + tid];
    __syncthreads();
    int sl = tid & 127, pt = tid >> 7;          // pt = 0..7
    int s = st * 128 + sl;
    float a = 0.f;
    if (s < Ssz) {
        const float* kb = kin + ((size_t)b * HID + pt * 32) * Ssz + s;
        const float* up = us + pt * 32;
        #pragma unroll
        for (int i = 0; i < 32; ++i) a += up[i] * kb[(size_t)i * Ssz];
    }
    part[pt][sl] = a;
    __syncthreads();
    if (tid < 128 && st * 128 + tid < Ssz) {
        float t = 0.f;
        #pragma unroll
        for (int p = 0; p < 8; ++p) t += part[p][tid];
        ws[OFF_SCORE + (size_t)b * Ssz + st * 128 + tid] = t;
    }
}

// ============ k3: v (512 blocks) + kbar (512 blocks) ========================
__global__ void __launch_bounds__(256)
k_v_kbar(const float* __restrict__ supp, const float* __restrict__ kin,
         float* __restrict__ ws) {
    int bid = blockIdx.x;
    int tid = threadIdx.x, lane = tid & 63, w = tid >> 6;

    if (bid < 512) {
        // ---- v role ----
        int cB = bid & 255, b = bid >> 8;
        int c0 = cB * 4;
        const float4* sp4 = (const float4*)(supp + ((size_t)b * Cch + c0) * Ssz);
        const float4* w04 = (const float4*)(ws + OFF_WMAP + (size_t)(b * 3 + 0) * Ssz);
        const float4* w14 = (const float4*)(ws + OFF_WMAP + (size_t)(b * 3 + 1) * Ssz);
        const float4* w24 = (const float4*)(ws + OFF_WMAP + (size_t)(b * 3 + 2) * Ssz);
        float a[4][3];
        #pragma unroll
        for (int cc = 0; cc < 4; ++cc) { a[cc][0] = 0; a[cc][1] = 0; a[cc][2] = 0; }
        #pragma unroll
        for (int j = 0; j < 4; ++j) {
            int idx = tid + 256 * j;
            if (idx < 900) {
                float4 g0 = w04[idx], g1 = w14[idx], g2 = w24[idx];
                #pragma unroll
                for (int cc = 0; cc < 4; ++cc) {
                    float4 f = sp4[cc * 900 + idx];
                    a[cc][0] += f.x * g0.x + f.y * g0.y + f.z * g0.z + f.w * g0.w;
                    a[cc][1] += f.x * g1.x + f.y * g1.y + f.z * g1.z + f.w * g1.w;
                    a[cc][2] += f.x * g2.x + f.y * g2.y + f.z * g2.z + f.w * g2.w;
                }
            }
        }
        #pragma unroll
        for (int m = 32; m >= 1; m >>= 1)
            #pragma unroll
            for (int cc = 0; cc < 4; ++cc) {
                a[cc][0] += __shfl_xor(a[cc][0], m, 64);
                a[cc][1] += __shfl_xor(a[cc][1], m, 64);
                a[cc][2] += __shfl_xor(a[cc][2], m, 64);
            }
        __shared__ float r[4][3][4];
        if (lane == 0)
            #pragma unroll
            for (int cc = 0; cc < 4; ++cc) {
                r[cc][0][w] = a[cc][0]; r[cc][1][w] = a[cc][1]; r[cc][2][w] = a[cc][2];
            }
        __syncthreads();
        if (tid < 12) {
            int cc = tid / 3, kk = tid - cc * 3;
            float s = r[cc][kk][0] + r[cc][kk][1] + r[cc][kk][2] + r[cc][kk][3];
            ws[OFF_V + (size_t)(b * 3 + kk) * Cch + c0 + cc] = s;
        }
        return;
    }

    // ---- kbar role ----
    int u2 = bid - 512;
    int i = u2 & 255, b = u2 >> 8;
    __shared__ float r1[4], r2[4];
    const float4* s4 = (const float4*)(ws + OFF_SCORE + (size_t)b * Ssz);
    float4 sv[4]; bool act[4];
    float mx = -INFINITY;
    #pragma unroll
    for (int j = 0; j < 4; ++j) {
        int idx = tid + 256 * j;
        act[j] = idx < 900;
        if (act[j]) {
            float4 v = s4[idx];
            sv[j] = v;
            mx = fmaxf(mx, fmaxf(fmaxf(v.x, v.y), fmaxf(v.z, v.w)));
        }
    }
    #pragma unroll
    for (int m = 32; m >= 1; m >>= 1) mx = fmaxf(mx, __shfl_xor(mx, m, 64));
    if (lane == 0) r1[w] = mx;
    __syncthreads();
    mx = fmaxf(fmaxf(r1[0], r1[1]), fmaxf(r1[2], r1[3]));
    __syncthreads();
    const float4* kr = (const float4*)(kin + ((size_t)b * HID + i) * Ssz);
    float se = 0.f, wsum = 0.f;
    #pragma unroll
    for (int j = 0; j < 4; ++j) {
        if (act[j]) {
            int idx = tid + 256 * j;
            float4 v = sv[j];
            float ex = expf(v.x - mx), ey = expf(v.y - mx);
            float ez = expf(v.z - mx), ew = expf(v.w - mx);
            se += ex + ey + ez + ew;
            float4 k4 = kr[idx];
            wsum += ex * k4.x + ey * k4.y + ez * k4.z + ew * k4.w;
        }
    }
    #pragma unroll
    for (int m = 32; m >= 1; m >>= 1) {
        se += __shfl_xor(se, m, 64);
        wsum += __shfl_xor(wsum, m, 64);
    }
    if (lane == 0) { r1[w] = se; r2[w] = wsum; }
    __syncthreads();
    if (tid == 0) {
        float seT = r1[0] + r1[1] + r1[2] + r1[3];
        float wsT = r2[0] + r2[1] + r2[2] + r2[3];
        ws[OFF_KBAR + b * HID + i] = wsT / seT;
    }
}

// ============ k4: dot planes (480 blocks) + apa-out (2 blocks) ==============
__global__ void __launch_bounds__(256)
k_dot_apa(const float* __restrict__ query, const float* __restrict__ w_k,
          const float* __restrict__ w_proj, const float* __restrict__ b_proj,
          const float* __restrict__ proto, float* __restrict__ ws,
          float* __restrict__ out) {
    int bid = blockIdx.x;
    int tid = threadIdx.x, lane = tid & 63, wv = tid >> 6;

    if (bid < 480) {
        int qt = bid % 15, cc = (bid / 15) & 15, b = bid / 240;
        int q = qt * 256 + tid;
        if (q < Ssz) {
            const float* v0 = ws + OFF_V + (size_t)(b * 3 + 0) * Cch;
            const float* v1 = ws + OFF_V + (size_t)(b * 3 + 1) * Cch;
            const float* v2 = ws + OFF_V + (size_t)(b * 3 + 2) * Cch;
            float a0 = 0, a1 = 0, a2 = 0;
            int c0 = cc * 64;
            #pragma unroll 8
            for (int c = c0; c < c0 + 64; ++c) {
                float qv = query[((size_t)b * Cch + c) * Ssz + q];
                a0 += qv * v0[c]; a1 += qv * v1[c]; a2 += qv * v2[c];
            }
            float* dst = ws + OFF_DOT + (size_t)(b * 3) * Ssz + q;
            atomicAdd(&dst[0], a0);
            atomicAdd(&dst[Ssz], a1);
            atomicAdd(&dst[2 * Ssz], a2);
        }
        return;
    }

    // ---- apa-out role ----
    int b = bid - 480;
    __shared__ float4 kbs[64];
    __shared__ float o1s[256];
    if (tid < 64) kbs[tid] = ((const float4*)(ws + OFF_KBAR + b * HID))[tid];
    __syncthreads();
    float4 kb4 = kbs[lane];
    const float4* wk4 = (const float4*)w_k;
    #pragma unroll 8
    for (int r = 0; r < 64; ++r) {
        int h = wv * 64 + r;
        float4 f = wk4[(size_t)h * 64 + lane];
        float p = f.x * kb4.x + f.y * kb4.y + f.z * kb4.z + f.w * kb4.w;
        #pragma unroll
        for (int m = 32; m >= 1; m >>= 1) p += __shfl_xor(p, m, 64);
        if (lane == 0) o1s[h] = p;
    }
    __syncthreads();
    float a = 0.f;
    #pragma unroll 4
    for (int d = 0; d < HID; ++d) a += o1s[d] * w_proj[(size_t)d * HID + tid];
    out[9578 + b * HID + tid] = a + b_proj[tid] + proto[b * HID + tid];
}

// ============ k5: sim x3 planes fused with corr-final (2 blocks) ============
__global__ void __launch_bounds__(1024)
k_simcorr(const float* __restrict__ weight, float* __restrict__ ws,
          float* __restrict__ out) {
    __shared__ float sA[66 * LPITCH];
    __shared__ float sB[66 * LPITCH];
    __shared__ float sF[Ssz];
    __shared__ float rmn[16], rmx[16];
    int b = blockIdx.x;
    int tid = threadIdx.x;
    int lane = tid & 63, wv = tid >> 6;

    for (int kt = 0; kt < 3; ++kt) {
        __syncthreads();   // protect sA/sB/rmn reuse across iterations
        const float* dp0 = ws + OFF_DOT + (size_t)(b * 3 + kt) * Ssz;
        for (int i = tid; i < 66 * LPITCH; i += 1024) {
            int r = i / LPITCH, col = i - r * LPITCH;
            int y = r - 3, x = col - 4;
            float s = 0.f;
            if (y >= 0 && y < Hh && x >= 0 && x < Hh) s = dp0[y * Hh + x];
            sA[i] = s;
        }
        __syncthreads();
        if (kt != 1) {
            for (int idx = tid; idx < 66 * 60; idx += 1024) {
                int r = idx / 60, x = idx - 60 * r;
                int base = r * LPITCH + 4 + x;
                if (kt == 0)
                    sB[base] = sA[base - 2] + sA[base - 1] + sA[base] + sA[base + 1] + sA[base + 2];
                else
                    sB[base] = sA[base - 3] + sA[base - 2] + sA[base - 1] + sA[base]
                             + sA[base + 1] + sA[base + 2] + sA[base + 3];
            }
        }
        __syncthreads();
        float norm = ((kt == 0) ? (1.f / 25.f) : (1.f / 7.f)) * (1.f / (float)Ssz);
        float vals[4];
        float vmin = INFINITY, vmax = -INFINITY;
        #pragma unroll
        for (int j = 0; j < 4; ++j) {
            int q = tid + j * 1024;
            if (q < Ssz) {
                int y = q / Hh, x = q - y * Hh;
                int base = (y + 3) * LPITCH + 4 + x;
                float s;
                if (kt == 0)
                    s = sB[base - 2*LPITCH] + sB[base - LPITCH] + sB[base]
                      + sB[base + LPITCH] + sB[base + 2*LPITCH];
                else if (kt == 1)
                    s = sA[base - 3*LPITCH] + sA[base - 2*LPITCH] + sA[base - LPITCH]
                      + sA[base] + sA[base + LPITCH] + sA[base + 2*LPITCH] + sA[base + 3*LPITCH];
                else
                    s = sB[base];
                float val = s * norm;
                vals[j] = val;
                vmin = fminf(vmin, val); vmax = fmaxf(vmax, val);
            }
        }
        #pragma unroll
        for (int m = 32; m >= 1; m >>= 1) {
            vmin = fminf(vmin, __shfl_xor(vmin, m, 64));
            vmax = fmaxf(vmax, __shfl_xor(vmax, m, 64));
        }
        if (lane == 0) { rmn[wv] = vmin; rmx[wv] = vmax; }
        __syncthreads();
        float mn = rmn[0], mx = rmx[0];
        #pragma unroll
        for (int ww = 1; ww < 16; ++ww) {
            mn = fminf(mn, rmn[ww]); mx = fmaxf(mx, rmx[ww]);
        }
        float inv = 1.f / (mx - mn + EPSF);
        #pragma unroll
        for (int j = 0; j < 4; ++j) {
            int q = tid + j * 1024;
            if (q < Ssz) {
                float nv = (vals[j] - mn) * inv;
                if (kt == 0) sF[q] = nv; else sF[q] += nv;
            }
        }
    }
    __syncthreads();

    // ---- corr final ----
    float wq3 = weight[b] * (1.f / 3.f);
    #pragma unroll
    for (int j = 0; j < 4; ++j) {
        int q = tid + j * 1024;
        if (q < Ssz) out[b * Ssz + q] = wq3 * sF[q];
    }
    #pragma unroll
    for (int j = 0; j < 2; ++j) {
        int o = tid + j * 1024;
        if (o >= 1189) continue;
        int O, p, outi;
        if (o < 900)       { O = 30; p = o;        outi = 7200 + b * 900 + p; }
        else if (o < 1125) { O = 15; p = o - 900;  outi = 9000 + b * 225 + p; }
        else               { O = 8;  p = o - 1125; outi = 9450 + b * 64 + p; }
        int y = p / O, x = p - y * O;
        float sc = 59.f / (float)(O - 1);
        float py = y * sc, px = x * sc;
        int y0 = (int)floorf(py), x0 = (int)floorf(px);
        int y1 = min(y0 + 1, 59), x1 = min(x0 + 1, 59);
        float wy = py - y0, wx = px - x0;
        float v = sF[y0 * 60 + x0] * (1.f - wy) * (1.f - wx)
                + sF[y1 * 60 + x0] * wy * (1.f - wx)
                + sF[y0 * 60 + x1] * (1.f - wy) * wx
                + sF[y1 * 60 + x1] * wy * wx;
        out[outi] = wq3 * v;
    }
}

extern "C" void kernel_launch(void* const* d_in, const int* in_sizes, int n_in,
                              void* d_out, int out_size, void* d_ws, size_t ws_size,
                              hipStream_t stream) {
    const float* weight = (const float*)d_in[0];
    const float* query  = (const float*)d_in[1];
    const float* supp   = (const float*)d_in[2];
    const float* masks  = (const float*)d_in[3];
    const float* kin    = (const float*)d_in[4];
    const float* text   = (const float*)d_in[5];
    const float* proto  = (const float*)d_in[6];
    const float* w_q    = (const float*)d_in[7];
    const float* w_k    = (const float*)d_in[8];
    const float* w_bl   = (const float*)d_in[9];
    const float* w_proj = (const float*)d_in[10];
    const float* b_proj = (const float*)d_in[11];
    float* out = (float*)d_out;
    float* ws  = (float*)d_ws;

    // zero atomic accumulator planes (SN2 + DOT)
    hipMemsetAsync(ws, 0, (size_t)OFF_WMAP * sizeof(float), stream);

    k_pool_u<<<514, 256, 0, stream>>>(supp, masks, text, proto, w_q, w_bl, w_k, ws);
    k_wmap_score<<<82, 1024, 0, stream>>>(masks, kin, ws);
    k_v_kbar<<<1024, 256, 0, stream>>>(supp, kin, ws);
    k_dot_apa<<<482, 256, 0, stream>>>(query, w_k, w_proj, b_proj, proto, ws, out);
    k_simcorr<<<Bsz, 1024, 0, stream>>>(weight, ws, out);
}

// Round 8
// 246.303 us; speedup vs baseline: 1.1124x; 1.1124x over previous
//
#include <hip/hip_runtime.h>
#include <math.h>

#define EPSF 1e-7f
#define Bsz 2
#define Cch 1024
#define Hh 60
#define Ssz 3600
#define HID 256
#define TDIM 300
#define MH 473

// pool tiling
#define TROWS 15
#define LROWS 21          // TROWS + 6 halo
#define LPITCH 68         // 4-col zero pad both sides of 60 cols
#define CPG 8             // channels per block (processed as 4 float2 pairs)

// workspace layout (float offsets)
// [0, 43200) zeroed by hipMemsetAsync each launch (SN2 + DOT atomic planes)
#define OFF_SN2    0               // 6*3600 sum over channels of pool^2 (atomic)
#define OFF_DOT    21600           // 6*3600 dot planes (atomic)
#define OFF_WMAP   43200           // 6*3600  mask-premultiplied pool(1/sn)
#define OFF_V      64800           // 6*1024
#define OFF_SCORE  70944           // 2*3600
#define OFF_KBAR   78144           // 2*256
#define OFF_U      78656           // 2*256

// ============ k1: u-GEMV chain (bid 0-1, FIRST so it overlaps) + pool =======
// pool: R6-proven LDS float2 version (h7 inline, 28560B LDS)
__global__ void __launch_bounds__(256)
k_pool_u(const float* __restrict__ supp, const float* __restrict__ masks,
         const float* __restrict__ text, const float* __restrict__ proto,
         const float* __restrict__ w_q,  const float* __restrict__ w_bl,
         const float* __restrict__ w_k,  float* __restrict__ ws) {
    __shared__ __align__(16) char smem[28560];
    int tid = threadIdx.x;
    int bid = blockIdx.x;

    if (bid < 2) {
        // ---- u role: u = w_k^T (w_bl^T (w_q^T [text;proto])), 4-wave float4.
        // bid 0-1 so these latency-bound blocks launch FIRST and hide under pool.
        int b = bid;
        int lane = tid & 63, wv = tid >> 6;
        float4* p4  = (float4*)smem;            // [4][64]
        float*  pf  = (float*)smem;
        float*  xs  = (float*)(smem + 4096);    // 556
        float*  qxs = (float*)(smem + 6400);    // 256
        float*  qws = (float*)(smem + 7424);    // 256
        const float4* wq4  = (const float4*)w_q;
        const float4* wbl4 = (const float4*)w_bl;
        const float4* wk4  = (const float4*)w_k;

        #pragma unroll
        for (int j = 0; j < 3; ++j) {
            int e = tid + 256 * j;
            if (e < TDIM) xs[e] = text[b * TDIM + e];
            else if (e < TDIM + HID) xs[e] = proto[b * HID + e - TDIM];
        }
        __syncthreads();
        float4 acc = {0.f, 0.f, 0.f, 0.f};
        #pragma unroll 4
        for (int j = 0; j < 139; ++j) {
            int e = wv + 4 * j;
            if (e < TDIM + HID) {
                float x = xs[e];
                float4 f = wq4[(size_t)e * 64 + lane];
                acc.x += x * f.x; acc.y += x * f.y; acc.z += x * f.z; acc.w += x * f.w;
            }
        }
        p4[wv * 64 + lane] = acc;
        __syncthreads();
        qxs[tid] = pf[tid] + pf[256 + tid] + pf[512 + tid] + pf[768 + tid];
        __syncthreads();

        acc.x = acc.y = acc.z = acc.w = 0.f;
        #pragma unroll 4
        for (int j = 0; j < 64; ++j) {
            int e = wv + 4 * j;
            float x = qxs[e];
            float4 f = wbl4[(size_t)e * 64 + lane];
            acc.x += x * f.x; acc.y += x * f.y; acc.z += x * f.z; acc.w += x * f.w;
        }
        p4[wv * 64 + lane] = acc;
        __syncthreads();
        qws[tid] = pf[tid] + pf[256 + tid] + pf[512 + tid] + pf[768 + tid];
        __syncthreads();

        acc.x = acc.y = acc.z = acc.w = 0.f;
        #pragma unroll 4
        for (int j = 0; j < 64; ++j) {
            int e = wv + 4 * j;
            float x = qws[e];
            float4 f = wk4[(size_t)e * 64 + lane];
            acc.x += x * f.x; acc.y += x * f.y; acc.z += x * f.z; acc.w += x * f.w;
        }
        p4[wv * 64 + lane] = acc;
        __syncthreads();
        ws[OFF_U + b * HID + tid] = pf[tid] + pf[256 + tid] + pf[512 + tid] + pf[768 + tid];
        return;
    }

    // ---- pool role: bid2 = bid - 2 ----
    float*  mk  = (float*) smem;             // 1428 floats
    float2* raw = (float2*)(smem + 5712);    // 1428 float2
    float2* h5s = (float2*)(smem + 17136);   // 1428 float2

    int bid2 = bid - 2;
    int tile = bid2 & 3, cgi = (bid2 >> 2) & 127, b = bid2 >> 9;
    int y0 = tile * TROWS;

    const float2 z2 = {0.f, 0.f};
    for (int i = tid; i < LROWS * LPITCH; i += 256) {
        mk[i] = 0.f; raw[i] = z2; h5s[i] = z2;
    }
    __syncthreads();

    int lr[5], lx[5]; bool lv[5], la[5];
    #pragma unroll
    for (int j = 0; j < 5; ++j) {
        int idx = tid + 256 * j;
        int r = idx / 60, x = idx - 60 * r;
        lr[j] = r; lx[j] = x;
        la[j] = idx < 1260;
        int iy = y0 - 3 + r;
        lv[j] = la[j] && (iy >= 0) && (iy < Hh);
    }
    #pragma unroll
    for (int j = 0; j < 5; ++j)
        if (lv[j]) {
            int iy = y0 - 3 + lr[j];
            mk[lr[j] * LPITCH + 4 + lx[j]] =
                masks[(size_t)b * MH * MH + (size_t)(iy * 8) * MH + lx[j] * 8];
        }

    int orow[4], ox[4]; bool ov[4];
    #pragma unroll
    for (int j = 0; j < 4; ++j) {
        int o = tid + 256 * j;
        int oy = o / 60, x = o - 60 * oy;
        orow[j] = oy + 3; ox[j] = x; ov[j] = o < 900;
    }
    float a0[4] = {0,0,0,0}, a1[4] = {0,0,0,0}, a2[4] = {0,0,0,0};

    const float* chbase = supp + ((size_t)b * Cch + (size_t)cgi * CPG) * Ssz + (y0 - 3) * 60;
    float pf0[5], pf1[5];
    #pragma unroll
    for (int j = 0; j < 5; ++j) {
        pf0[j] = lv[j] ? chbase[tid + 256 * j] : 0.f;
        pf1[j] = lv[j] ? chbase[Ssz + tid + 256 * j] : 0.f;
    }

    for (int p = 0; p < CPG / 2; ++p) {
        __syncthreads();
        #pragma unroll
        for (int j = 0; j < 5; ++j)
            if (lv[j]) {
                float m = mk[lr[j] * LPITCH + 4 + lx[j]];
                raw[lr[j] * LPITCH + 4 + lx[j]] = make_float2(pf0[j] * m, pf1[j] * m);
            }
        __syncthreads();
        #pragma unroll
        for (int j = 0; j < 5; ++j)
            if (la[j]) {
                int base = lr[j] * LPITCH + 4 + lx[j];
                float2 m2 = raw[base - 2], m1 = raw[base - 1];
                float2 c0 = raw[base], p1 = raw[base + 1], p2 = raw[base + 2];
                float2 h5;
                h5.x = m2.x + m1.x + c0.x + p1.x + p2.x;
                h5.y = m2.y + m1.y + c0.y + p1.y + p2.y;
                h5s[base] = h5;
            }
        __syncthreads();
        if (p + 1 < CPG / 2) {
            const float* nb = chbase + (size_t)(2 * p + 2) * Ssz;
            #pragma unroll
            for (int j = 0; j < 5; ++j) {
                pf0[j] = lv[j] ? nb[tid + 256 * j] : 0.f;
                pf1[j] = lv[j] ? nb[Ssz + tid + 256 * j] : 0.f;
            }
        }
        #pragma unroll
        for (int j = 0; j < 4; ++j)
            if (ov[j]) {
                int base = orow[j] * LPITCH + 4 + ox[j];
                float2 sa = h5s[base - 2*LPITCH], sb = h5s[base - LPITCH], sc0 = h5s[base];
                float2 sd = h5s[base + LPITCH], se = h5s[base + 2*LPITCH];
                float p55x = (sa.x + sb.x + sc0.x + sd.x + se.x) * (1.f / 25.f);
                float p55y = (sa.y + sb.y + sc0.y + sd.y + se.y) * (1.f / 25.f);
                float2 ra = raw[base - 3*LPITCH], rb = raw[base - 2*LPITCH], rc = raw[base - LPITCH];
                float2 rd = raw[base], re = raw[base + LPITCH], rf = raw[base + 2*LPITCH], rg = raw[base + 3*LPITCH];
                float p71x = (ra.x + rb.x + rc.x + rd.x + re.x + rf.x + rg.x) * (1.f / 7.f);
                float p71y = (ra.y + rb.y + rc.y + rd.y + re.y + rf.y + rg.y) * (1.f / 7.f);
                float2 m3o = raw[base - 3], p3o = raw[base + 3];    // h7 inline
                float p17x = (sc0.x + m3o.x + p3o.x) * (1.f / 7.f);
                float p17y = (sc0.y + m3o.y + p3o.y) * (1.f / 7.f);
                a0[j] += p55x * p55x + p55y * p55y;
                a1[j] += p71x * p71x + p71y * p71y;
                a2[j] += p17x * p17x + p17y * p17y;
            }
    }
    float* acc = ws + OFF_SN2 + (size_t)(b * 3) * Ssz;
    #pragma unroll
    for (int j = 0; j < 4; ++j)
        if (ov[j]) {
            int q = (y0 + orow[j] - 3) * 60 + ox[j];
            atomicAdd(&acc[q], a0[j]);
            atomicAdd(&acc[Ssz + q], a1[j]);
            atomicAdd(&acc[2 * Ssz + q], a2[j]);
        }
}

// ============ k2: wmap (24 blocks) + score strips (58 blocks) ===============
__global__ void __launch_bounds__(1024)
k_wmap_score(const float* __restrict__ masks, const float* __restrict__ kin,
             float* __restrict__ ws) {
    int bid = blockIdx.x;
    int tid = threadIdx.x;

    if (bid < 24) {
        // ---- wmap role ----
        __shared__ float inv[LROWS * LPITCH];
        int tile = bid & 3, bk = bid >> 2;
        int b = bk / 3, kt = bk % 3;
        int y0 = tile * TROWS;
        for (int i = tid; i < LROWS * LPITCH; i += 1024) inv[i] = 0.f;
        __syncthreads();
        const float* pp = ws + OFF_SN2 + (size_t)bk * Ssz;
        #pragma unroll
        for (int j = 0; j < 2; ++j) {
            int idx = tid + 1024 * j;
            if (idx < 1260) {
                int r = idx / 60, x = idx - 60 * r;
                int iy = y0 - 3 + r;
                if (iy >= 0 && iy < Hh)
                    inv[r * LPITCH + 4 + x] = 1.0f / sqrtf(fmaxf(pp[iy * 60 + x], 1e-30f));
            }
        }
        __syncthreads();
        int kh = (kt == 0) ? 5 : (kt == 1) ? 7 : 1;
        int kw = (kt == 0) ? 5 : (kt == 2) ? 7 : 1;
        int rh = kh / 2, rw = kw / 2;
        float norm = 1.f / (float)(kh * kw);
        int o = tid;
        if (o < 900) {
            int oy = o / 60, x = o - 60 * oy;
            int base = (oy + 3) * LPITCH + 4 + x;
            float s = 0.f;
            for (int dy = -rh; dy <= rh; ++dy)
                for (int dx = -rw; dx <= rw; ++dx)
                    s += inv[base + dy * LPITCH + dx];
            int gy = y0 + oy;
            float m = masks[(size_t)b * MH * MH + (size_t)(gy * 8) * MH + x * 8];
            ws[OFF_WMAP + (size_t)bk * Ssz + gy * 60 + x] = s * norm * m;
        }
        return;
    }

    // ---- score role: 128 s-values, 8-way i-split, LDS reduce ----
    __shared__ float us[HID];
    __shared__ float part[8][128];
    int idx = bid - 24;            // 0..57
    int st = idx % 29, b = idx / 29;
    if (tid < HID) us[tid] = ws[OFF_U + b * HID + tid];
    __syncthreads();
    int sl = tid & 127, pt = tid >> 7;          // pt = 0..7
    int s = st * 128 + sl;
    float a = 0.f;
    if (s < Ssz) {
        const float* kb = kin + ((size_t)b * HID + pt * 32) * Ssz + s;
        const float* up = us + pt * 32;
        #pragma unroll
        for (int i = 0; i < 32; ++i) a += up[i] * kb[(size_t)i * Ssz];
    }
    part[pt][sl] = a;
    __syncthreads();
    if (tid < 128 && st * 128 + tid < Ssz) {
        float t = 0.f;
        #pragma unroll
        for (int p = 0; p < 8; ++p) t += part[p][tid];
        ws[OFF_SCORE + (size_t)b * Ssz + st * 128 + tid] = t;
    }
}

// ============ k3: v (512 blocks) + kbar (512 blocks) ========================
__global__ void __launch_bounds__(256)
k_v_kbar(const float* __restrict__ supp, const float* __restrict__ kin,
         float* __restrict__ ws) {
    int bid = blockIdx.x;
    int tid = threadIdx.x, lane = tid & 63, w = tid >> 6;

    if (bid < 512) {
        // ---- v role ----
        int cB = bid & 255, b = bid >> 8;
        int c0 = cB * 4;
        const float4* sp4 = (const float4*)(supp + ((size_t)b * Cch + c0) * Ssz);
        const float4* w04 = (const float4*)(ws + OFF_WMAP + (size_t)(b * 3 + 0) * Ssz);
        const float4* w14 = (const float4*)(ws + OFF_WMAP + (size_t)(b * 3 + 1) * Ssz);
        const float4* w24 = (const float4*)(ws + OFF_WMAP + (size_t)(b * 3 + 2) * Ssz);
        float a[4][3];
        #pragma unroll
        for (int cc = 0; cc < 4; ++cc) { a[cc][0] = 0; a[cc][1] = 0; a[cc][2] = 0; }
        #pragma unroll
        for (int j = 0; j < 4; ++j) {
            int idx = tid + 256 * j;
            if (idx < 900) {
                float4 g0 = w04[idx], g1 = w14[idx], g2 = w24[idx];
                #pragma unroll
                for (int cc = 0; cc < 4; ++cc) {
                    float4 f = sp4[cc * 900 + idx];
                    a[cc][0] += f.x * g0.x + f.y * g0.y + f.z * g0.z + f.w * g0.w;
                    a[cc][1] += f.x * g1.x + f.y * g1.y + f.z * g1.z + f.w * g1.w;
                    a[cc][2] += f.x * g2.x + f.y * g2.y + f.z * g2.z + f.w * g2.w;
                }
            }
        }
        #pragma unroll
        for (int m = 32; m >= 1; m >>= 1)
            #pragma unroll
            for (int cc = 0; cc < 4; ++cc) {
                a[cc][0] += __shfl_xor(a[cc][0], m, 64);
                a[cc][1] += __shfl_xor(a[cc][1], m, 64);
                a[cc][2] += __shfl_xor(a[cc][2], m, 64);
            }
        __shared__ float r[4][3][4];
        if (lane == 0)
            #pragma unroll
            for (int cc = 0; cc < 4; ++cc) {
                r[cc][0][w] = a[cc][0]; r[cc][1][w] = a[cc][1]; r[cc][2][w] = a[cc][2];
            }
        __syncthreads();
        if (tid < 12) {
            int cc = tid / 3, kk = tid - cc * 3;
            float s = r[cc][kk][0] + r[cc][kk][1] + r[cc][kk][2] + r[cc][kk][3];
            ws[OFF_V + (size_t)(b * 3 + kk) * Cch + c0 + cc] = s;
        }
        return;
    }

    // ---- kbar role ----
    int u2 = bid - 512;
    int i = u2 & 255, b = u2 >> 8;
    __shared__ float r1[4], r2[4];
    const float4* s4 = (const float4*)(ws + OFF_SCORE + (size_t)b * Ssz);
    float4 sv[4]; bool act[4];
    float mx = -INFINITY;
    #pragma unroll
    for (int j = 0; j < 4; ++j) {
        int idx = tid + 256 * j;
        act[j] = idx < 900;
        if (act[j]) {
            float4 v = s4[idx];
            sv[j] = v;
            mx = fmaxf(mx, fmaxf(fmaxf(v.x, v.y), fmaxf(v.z, v.w)));
        }
    }
    #pragma unroll
    for (int m = 32; m >= 1; m >>= 1) mx = fmaxf(mx, __shfl_xor(mx, m, 64));
    if (lane == 0) r1[w] = mx;
    __syncthreads();
    mx = fmaxf(fmaxf(r1[0], r1[1]), fmaxf(r1[2], r1[3]));
    __syncthreads();
    const float4* kr = (const float4*)(kin + ((size_t)b * HID + i) * Ssz);
    float se = 0.f, wsum = 0.f;
    #pragma unroll
    for (int j = 0; j < 4; ++j) {
        if (act[j]) {
            int idx = tid + 256 * j;
            float4 v = sv[j];
            float ex = expf(v.x - mx), ey = expf(v.y - mx);
            float ez = expf(v.z - mx), ew = expf(v.w - mx);
            se += ex + ey + ez + ew;
            float4 k4 = kr[idx];
            wsum += ex * k4.x + ey * k4.y + ez * k4.z + ew * k4.w;
        }
    }
    #pragma unroll
    for (int m = 32; m >= 1; m >>= 1) {
        se += __shfl_xor(se, m, 64);
        wsum += __shfl_xor(wsum, m, 64);
    }
    if (lane == 0) { r1[w] = se; r2[w] = wsum; }
    __syncthreads();
    if (tid == 0) {
        float seT = r1[0] + r1[1] + r1[2] + r1[3];
        float wsT = r2[0] + r2[1] + r2[2] + r2[3];
        ws[OFF_KBAR + b * HID + i] = wsT / seT;
    }
}

// ============ k4: apa-out (bid 0-1, FIRST) + dot planes (bid 2-481) =========
__global__ void __launch_bounds__(256)
k_dot_apa(const float* __restrict__ query, const float* __restrict__ w_k,
          const float* __restrict__ w_proj, const float* __restrict__ b_proj,
          const float* __restrict__ proto, float* __restrict__ ws,
          float* __restrict__ out) {
    int bid = blockIdx.x;
    int tid = threadIdx.x, lane = tid & 63, wv = tid >> 6;

    if (bid < 2) {
        // ---- apa-out role (latency-bound, launch first to hide under dot) ----
        int b = bid;
        __shared__ float4 kbs[64];
        __shared__ float o1s[256];
        if (tid < 64) kbs[tid] = ((const float4*)(ws + OFF_KBAR + b * HID))[tid];
        __syncthreads();
        float4 kb4 = kbs[lane];
        const float4* wk4 = (const float4*)w_k;
        #pragma unroll 8
        for (int r = 0; r < 64; ++r) {
            int h = wv * 64 + r;
            float4 f = wk4[(size_t)h * 64 + lane];
            float p = f.x * kb4.x + f.y * kb4.y + f.z * kb4.z + f.w * kb4.w;
            #pragma unroll
            for (int m = 32; m >= 1; m >>= 1) p += __shfl_xor(p, m, 64);
            if (lane == 0) o1s[h] = p;
        }
        __syncthreads();
        float a = 0.f;
        #pragma unroll 4
        for (int d = 0; d < HID; ++d) a += o1s[d] * w_proj[(size_t)d * HID + tid];
        out[9578 + b * HID + tid] = a + b_proj[tid] + proto[b * HID + tid];
        return;
    }

    // ---- dot role ----
    int u2 = bid - 2;
    int qt = u2 % 15, cc = (u2 / 15) & 15, b = u2 / 240;
    int q = qt * 256 + tid;
    if (q < Ssz) {
        const float* v0 = ws + OFF_V + (size_t)(b * 3 + 0) * Cch;
        const float* v1 = ws + OFF_V + (size_t)(b * 3 + 1) * Cch;
        const float* v2 = ws + OFF_V + (size_t)(b * 3 + 2) * Cch;
        float a0 = 0, a1 = 0, a2 = 0;
        int c0 = cc * 64;
        #pragma unroll 8
        for (int c = c0; c < c0 + 64; ++c) {
            float qv = query[((size_t)b * Cch + c) * Ssz + q];
            a0 += qv * v0[c]; a1 += qv * v1[c]; a2 += qv * v2[c];
        }
        float* dst = ws + OFF_DOT + (size_t)(b * 3) * Ssz + q;
        atomicAdd(&dst[0], a0);
        atomicAdd(&dst[Ssz], a1);
        atomicAdd(&dst[2 * Ssz], a2);
    }
}

// ============ k5: sim x3 planes fused with corr-final (2 blocks) ============
__global__ void __launch_bounds__(1024)
k_simcorr(const float* __restrict__ weight, float* __restrict__ ws,
          float* __restrict__ out) {
    __shared__ float sA[66 * LPITCH];
    __shared__ float sB[66 * LPITCH];
    __shared__ float sF[Ssz];
    __shared__ float rmn[16], rmx[16];
    int b = blockIdx.x;
    int tid = threadIdx.x;
    int lane = tid & 63, wv = tid >> 6;

    for (int kt = 0; kt < 3; ++kt) {
        __syncthreads();   // protect sA/sB/rmn reuse across iterations
        const float* dp0 = ws + OFF_DOT + (size_t)(b * 3 + kt) * Ssz;
        for (int i = tid; i < 66 * LPITCH; i += 1024) {
            int r = i / LPITCH, col = i - r * LPITCH;
            int y = r - 3, x = col - 4;
            float s = 0.f;
            if (y >= 0 && y < Hh && x >= 0 && x < Hh) s = dp0[y * Hh + x];
            sA[i] = s;
        }
        __syncthreads();
        if (kt != 1) {
            for (int idx = tid; idx < 66 * 60; idx += 1024) {
                int r = idx / 60, x = idx - 60 * r;
                int base = r * LPITCH + 4 + x;
                if (kt == 0)
                    sB[base] = sA[base - 2] + sA[base - 1] + sA[base] + sA[base + 1] + sA[base + 2];
                else
                    sB[base] = sA[base - 3] + sA[base - 2] + sA[base - 1] + sA[base]
                             + sA[base + 1] + sA[base + 2] + sA[base + 3];
            }
        }
        __syncthreads();
        float norm = ((kt == 0) ? (1.f / 25.f) : (1.f / 7.f)) * (1.f / (float)Ssz);
        float vals[4];
        float vmin = INFINITY, vmax = -INFINITY;
        #pragma unroll
        for (int j = 0; j < 4; ++j) {
            int q = tid + j * 1024;
            if (q < Ssz) {
                int y = q / Hh, x = q - y * Hh;
                int base = (y + 3) * LPITCH + 4 + x;
                float s;
                if (kt == 0)
                    s = sB[base - 2*LPITCH] + sB[base - LPITCH] + sB[base]
                      + sB[base + LPITCH] + sB[base + 2*LPITCH];
                else if (kt == 1)
                    s = sA[base - 3*LPITCH] + sA[base - 2*LPITCH] + sA[base - LPITCH]
                      + sA[base] + sA[base + LPITCH] + sA[base + 2*LPITCH] + sA[base + 3*LPITCH];
                else
                    s = sB[base];
                float val = s * norm;
                vals[j] = val;
                vmin = fminf(vmin, val); vmax = fmaxf(vmax, val);
            }
        }
        #pragma unroll
        for (int m = 32; m >= 1; m >>= 1) {
            vmin = fminf(vmin, __shfl_xor(vmin, m, 64));
            vmax = fmaxf(vmax, __shfl_xor(vmax, m, 64));
        }
        if (lane == 0) { rmn[wv] = vmin; rmx[wv] = vmax; }
        __syncthreads();
        float mn = rmn[0], mx = rmx[0];
        #pragma unroll
        for (int ww = 1; ww < 16; ++ww) {
            mn = fminf(mn, rmn[ww]); mx = fmaxf(mx, rmx[ww]);
        }
        float inv = 1.f / (mx - mn + EPSF);
        #pragma unroll
        for (int j = 0; j < 4; ++j) {
            int q = tid + j * 1024;
            if (q < Ssz) {
                float nv = (vals[j] - mn) * inv;
                if (kt == 0) sF[q] = nv; else sF[q] += nv;
            }
        }
    }
    __syncthreads();

    // ---- corr final ----
    float wq3 = weight[b] * (1.f / 3.f);
    #pragma unroll
    for (int j = 0; j < 4; ++j) {
        int q = tid + j * 1024;
        if (q < Ssz) out[b * Ssz + q] = wq3 * sF[q];
    }
    #pragma unroll
    for (int j = 0; j < 2; ++j) {
        int o = tid + j * 1024;
        if (o >= 1189) continue;
        int O, p, outi;
        if (o < 900)       { O = 30; p = o;        outi = 7200 + b * 900 + p; }
        else if (o < 1125) { O = 15; p = o - 900;  outi = 9000 + b * 225 + p; }
        else               { O = 8;  p = o - 1125; outi = 9450 + b * 64 + p; }
        int y = p / O, x = p - y * O;
        float sc = 59.f / (float)(O - 1);
        float py = y * sc, px = x * sc;
        int y0 = (int)floorf(py), x0 = (int)floorf(px);
        int y1 = min(y0 + 1, 59), x1 = min(x0 + 1, 59);
        float wy = py - y0, wx = px - x0;
        float v = sF[y0 * 60 + x0] * (1.f - wy) * (1.f - wx)
                + sF[y1 * 60 + x0] * wy * (1.f - wx)
                + sF[y0 * 60 + x1] * (1.f - wy) * wx
                + sF[y1 * 60 + x1] * wy * wx;
        out[outi] = wq3 * v;
    }
}

extern "C" void kernel_launch(void* const* d_in, const int* in_sizes, int n_in,
                              void* d_out, int out_size, void* d_ws, size_t ws_size,
                              hipStream_t stream) {
    const float* weight = (const float*)d_in[0];
    const float* query  = (const float*)d_in[1];
    const float* supp   = (const float*)d_in[2];
    const float* masks  = (const float*)d_in[3];
    const float* kin    = (const float*)d_in[4];
    const float* text   = (const float*)d_in[5];
    const float* proto  = (const float*)d_in[6];
    const float* w_q    = (const float*)d_in[7];
    const float* w_k    = (const float*)d_in[8];
    const float* w_bl   = (const float*)d_in[9];
    const float* w_proj = (const float*)d_in[10];
    const float* b_proj = (const float*)d_in[11];
    float* out = (float*)d_out;
    float* ws  = (float*)d_ws;

    // zero atomic accumulator planes (SN2 + DOT)
    hipMemsetAsync(ws, 0, (size_t)OFF_WMAP * sizeof(float), stream);

    k_pool_u<<<1026, 256, 0, stream>>>(supp, masks, text, proto, w_q, w_bl, w_k, ws);
    k_wmap_score<<<82, 1024, 0, stream>>>(masks, kin, ws);
    k_v_kbar<<<1024, 256, 0, stream>>>(supp, kin, ws);
    k_dot_apa<<<482, 256, 0, stream>>>(query, w_k, w_proj, b_proj, proto, ws, out);
    k_simcorr<<<Bsz, 1024, 0, stream>>>(weight, ws, out);
}

// Round 9
// 189.686 us; speedup vs baseline: 1.4445x; 1.2985x over previous
//
#include <hip/hip_runtime.h>
#include <math.h>

#define EPSF 1e-7f
#define Bsz 2
#define Cch 1024
#define Hh 60
#define Ssz 3600
#define HID 256
#define TDIM 300
#define MH 473

// pool tiling
#define TROWS 15
#define LROWS 21          // TROWS + 6 halo
#define LPITCH 68         // 4-col zero pad both sides of 60 cols
#define CPG 8             // channels per block (processed as 2 float4 passes)

// workspace layout (float offsets)
// [0, 43200) zeroed by hipMemsetAsync each launch (SN2 + DOT atomic planes)
#define OFF_SN2    0               // 6*3600 sum over channels of pool^2 (atomic)
#define OFF_DOT    21600           // 6*3600 dot planes (atomic)
#define OFF_WMAP   43200           // 6*3600  mask-premultiplied pool(1/sn)
#define OFF_V      64800           // 6*1024
#define OFF_NORM   70944           // 6*3600 normalized sim planes
#define OFF_SCORE  92544           // 2*3600
#define OFF_KBAR   99744           // 2*256
#define OFF_U      100256          // 2*256

// ---------------- pass A: pool^2 -> atomic SN2 planes (float4, h7 inline) ----
// LDS: mk 5712B + raw 22848B + h5s 22848B = 51408B -> 3 blocks/CU
__global__ void __launch_bounds__(256) k_pool_sn2(const float* __restrict__ supp,
                                                  const float* __restrict__ masks,
                                                  float* __restrict__ ws) {
    __shared__ float  mk[LROWS * LPITCH];
    __shared__ float4 raw[LROWS * LPITCH];
    __shared__ float4 h5s[LROWS * LPITCH];
    int tid = threadIdx.x;
    int tile = blockIdx.x;       // 0..3
    int cg = blockIdx.y;         // 0..127
    int b = blockIdx.z;          // 0..1
    int y0 = tile * TROWS;

    const float4 z4 = {0.f, 0.f, 0.f, 0.f};
    for (int i = tid; i < LROWS * LPITCH; i += 256) {
        mk[i] = 0.f; raw[i] = z4; h5s[i] = z4;
    }
    __syncthreads();

    int lr[5], lx[5]; bool lv[5], la[5];
    #pragma unroll
    for (int j = 0; j < 5; ++j) {
        int idx = tid + 256 * j;
        int r = idx / 60, x = idx - 60 * r;
        lr[j] = r; lx[j] = x;
        la[j] = idx < 1260;
        int iy = y0 - 3 + r;
        lv[j] = la[j] && (iy >= 0) && (iy < Hh);
    }
    #pragma unroll
    for (int j = 0; j < 5; ++j)
        if (lv[j]) {
            int iy = y0 - 3 + lr[j];
            mk[lr[j] * LPITCH + 4 + lx[j]] =
                masks[(size_t)b * MH * MH + (size_t)(iy * 8) * MH + lx[j] * 8];
        }

    int orow[4], ox[4]; bool ov[4];
    #pragma unroll
    for (int j = 0; j < 4; ++j) {
        int o = tid + 256 * j;
        int oy = o / 60, x = o - 60 * oy;
        orow[j] = oy + 3; ox[j] = x; ov[j] = o < 900;
    }
    float a0[4] = {0,0,0,0}, a1[4] = {0,0,0,0}, a2[4] = {0,0,0,0};

    const float* chbase = supp + ((size_t)b * Cch + (size_t)cg * CPG) * Ssz + (y0 - 3) * 60;
    float4 pf[5];
    #pragma unroll
    for (int j = 0; j < 5; ++j) {
        int idx = tid + 256 * j;
        pf[j] = z4;
        if (lv[j]) {
            pf[j].x = chbase[idx];
            pf[j].y = chbase[Ssz + idx];
            pf[j].z = chbase[2 * Ssz + idx];
            pf[j].w = chbase[3 * Ssz + idx];
        }
    }

    for (int p = 0; p < 2; ++p) {          // 2 passes x 4 channels
        __syncthreads();
        #pragma unroll
        for (int j = 0; j < 5; ++j)
            if (lv[j]) {
                float m = mk[lr[j] * LPITCH + 4 + lx[j]];
                float4 v = pf[j];
                raw[lr[j] * LPITCH + 4 + lx[j]] =
                    make_float4(v.x * m, v.y * m, v.z * m, v.w * m);
            }
        __syncthreads();
        #pragma unroll
        for (int j = 0; j < 5; ++j)
            if (la[j]) {
                int base = lr[j] * LPITCH + 4 + lx[j];
                float4 m2 = raw[base - 2], m1 = raw[base - 1];
                float4 c0 = raw[base], p1 = raw[base + 1], p2 = raw[base + 2];
                float4 h5;
                h5.x = m2.x + m1.x + c0.x + p1.x + p2.x;
                h5.y = m2.y + m1.y + c0.y + p1.y + p2.y;
                h5.z = m2.z + m1.z + c0.z + p1.z + p2.z;
                h5.w = m2.w + m1.w + c0.w + p1.w + p2.w;
                h5s[base] = h5;
            }
        __syncthreads();
        if (p == 0) {
            const float* nb = chbase + (size_t)4 * Ssz;
            #pragma unroll
            for (int j = 0; j < 5; ++j) {
                int idx = tid + 256 * j;
                pf[j] = z4;
                if (lv[j]) {
                    pf[j].x = nb[idx];
                    pf[j].y = nb[Ssz + idx];
                    pf[j].z = nb[2 * Ssz + idx];
                    pf[j].w = nb[3 * Ssz + idx];
                }
            }
        }
        #pragma unroll
        for (int j = 0; j < 4; ++j)
            if (ov[j]) {
                int base = orow[j] * LPITCH + 4 + ox[j];
                float4 sa = h5s[base - 2*LPITCH], sb = h5s[base - LPITCH], sc0 = h5s[base];
                float4 sd = h5s[base + LPITCH], se = h5s[base + 2*LPITCH];
                float p55x = (sa.x + sb.x + sc0.x + sd.x + se.x) * (1.f / 25.f);
                float p55y = (sa.y + sb.y + sc0.y + sd.y + se.y) * (1.f / 25.f);
                float p55z = (sa.z + sb.z + sc0.z + sd.z + se.z) * (1.f / 25.f);
                float p55w = (sa.w + sb.w + sc0.w + sd.w + se.w) * (1.f / 25.f);
                float4 ra = raw[base - 3*LPITCH], rb = raw[base - 2*LPITCH], rc = raw[base - LPITCH];
                float4 rd = raw[base], re = raw[base + LPITCH], rf = raw[base + 2*LPITCH], rg = raw[base + 3*LPITCH];
                float p71x = (ra.x + rb.x + rc.x + rd.x + re.x + rf.x + rg.x) * (1.f / 7.f);
                float p71y = (ra.y + rb.y + rc.y + rd.y + re.y + rf.y + rg.y) * (1.f / 7.f);
                float p71z = (ra.z + rb.z + rc.z + rd.z + re.z + rf.z + rg.z) * (1.f / 7.f);
                float p71w = (ra.w + rb.w + rc.w + rd.w + re.w + rf.w + rg.w) * (1.f / 7.f);
                float4 m3o = raw[base - 3], p3o = raw[base + 3];   // 1x7 inline
                float p17x = (sc0.x + m3o.x + p3o.x) * (1.f / 7.f);
                float p17y = (sc0.y + m3o.y + p3o.y) * (1.f / 7.f);
                float p17z = (sc0.z + m3o.z + p3o.z) * (1.f / 7.f);
                float p17w = (sc0.w + m3o.w + p3o.w) * (1.f / 7.f);
                a0[j] += p55x * p55x + p55y * p55y + p55z * p55z + p55w * p55w;
                a1[j] += p71x * p71x + p71y * p71y + p71z * p71z + p71w * p71w;
                a2[j] += p17x * p17x + p17y * p17y + p17z * p17z + p17w * p17w;
            }
    }
    float* acc = ws + OFF_SN2 + (size_t)(b * 3) * Ssz;
    #pragma unroll
    for (int j = 0; j < 4; ++j)
        if (ov[j]) {
            int q = (y0 + orow[j] - 3) * 60 + ox[j];
            atomicAdd(&acc[q], a0[j]);
            atomicAdd(&acc[Ssz + q], a1[j]);
            atomicAdd(&acc[2 * Ssz + q], a2[j]);
        }
}

// ---------------- wm[b][kt] = mask * pool_kt(1/sqrt(sn2)) -------------------
__global__ void __launch_bounds__(1024) k_wmap(const float* __restrict__ masks,
                                               float* __restrict__ ws) {
    __shared__ float inv[LROWS * LPITCH];
    int tile = blockIdx.x;       // 0..3
    int bk = blockIdx.y;         // 0..5 = b*3+kt
    int b = bk / 3, kt = bk % 3;
    int tid = threadIdx.x;
    int y0 = tile * TROWS;
    for (int i = tid; i < LROWS * LPITCH; i += 1024) inv[i] = 0.f;
    __syncthreads();
    const float* pp = ws + OFF_SN2 + (size_t)bk * Ssz;
    #pragma unroll
    for (int j = 0; j < 2; ++j) {
        int idx = tid + 1024 * j;
        if (idx < 1260) {
            int r = idx / 60, x = idx - 60 * r;
            int iy = y0 - 3 + r;
            if (iy >= 0 && iy < Hh) {
                int q = iy * 60 + x;
                float s = pp[q];
                inv[r * LPITCH + 4 + x] = 1.0f / sqrtf(fmaxf(s, 1e-30f));
            }
        }
    }
    __syncthreads();
    int kh = (kt == 0) ? 5 : (kt == 1) ? 7 : 1;
    int kw = (kt == 0) ? 5 : (kt == 2) ? 7 : 1;
    int rh = kh / 2, rw = kw / 2;
    float norm = 1.f / (float)(kh * kw);
    int o = tid;
    if (o < 900) {
        int oy = o / 60, x = o - 60 * oy;
        int base = (oy + 3) * LPITCH + 4 + x;
        float s = 0.f;
        for (int dy = -rh; dy <= rh; ++dy)
            for (int dx = -rw; dx <= rw; ++dx)
                s += inv[base + dy * LPITCH + dx];
        int gy = y0 + oy;
        float m = masks[(size_t)b * MH * MH + (size_t)(gy * 8) * MH + x * 8];
        ws[OFF_WMAP + (size_t)bk * Ssz + gy * 60 + x] = s * norm * m;
    }
}

// ---------------- v[b][kt][c] : 4 channels/block, wmap reused ---------------
__global__ void k_v(const float* __restrict__ supp, float* __restrict__ ws) {
    int cB = blockIdx.x, b = blockIdx.y;
    int tid = threadIdx.x, lane = tid & 63, w = tid >> 6;
    int c0 = cB * 4;
    const float4* sp4 = (const float4*)(supp + ((size_t)b * Cch + c0) * Ssz);
    const float4* w04 = (const float4*)(ws + OFF_WMAP + (size_t)(b * 3 + 0) * Ssz);
    const float4* w14 = (const float4*)(ws + OFF_WMAP + (size_t)(b * 3 + 1) * Ssz);
    const float4* w24 = (const float4*)(ws + OFF_WMAP + (size_t)(b * 3 + 2) * Ssz);
    float a[4][3];
    #pragma unroll
    for (int cc = 0; cc < 4; ++cc) { a[cc][0] = 0; a[cc][1] = 0; a[cc][2] = 0; }
    #pragma unroll
    for (int j = 0; j < 4; ++j) {
        int idx = tid + 256 * j;
        if (idx < 900) {
            float4 g0 = w04[idx], g1 = w14[idx], g2 = w24[idx];
            #pragma unroll
            for (int cc = 0; cc < 4; ++cc) {
                float4 f = sp4[cc * 900 + idx];
                a[cc][0] += f.x * g0.x + f.y * g0.y + f.z * g0.z + f.w * g0.w;
                a[cc][1] += f.x * g1.x + f.y * g1.y + f.z * g1.z + f.w * g1.w;
                a[cc][2] += f.x * g2.x + f.y * g2.y + f.z * g2.z + f.w * g2.w;
            }
        }
    }
    #pragma unroll
    for (int m = 32; m >= 1; m >>= 1)
        #pragma unroll
        for (int cc = 0; cc < 4; ++cc) {
            a[cc][0] += __shfl_xor(a[cc][0], m, 64);
            a[cc][1] += __shfl_xor(a[cc][1], m, 64);
            a[cc][2] += __shfl_xor(a[cc][2], m, 64);
        }
    __shared__ float r[4][3][4];
    if (lane == 0)
        #pragma unroll
        for (int cc = 0; cc < 4; ++cc) {
            r[cc][0][w] = a[cc][0]; r[cc][1][w] = a[cc][1]; r[cc][2][w] = a[cc][2];
        }
    __syncthreads();
    if (tid < 12) {
        int cc = tid / 3, kk = tid - cc * 3;
        float s = r[cc][kk][0] + r[cc][kk][1] + r[cc][kk][2] + r[cc][kk][3];
        ws[OFF_V + (size_t)(b * 3 + kk) * Cch + c0 + cc] = s;
    }
}

// ---------------- dot planes: atomic-accumulated over channel groups --------
__global__ void k_dot(const float* __restrict__ query, float* __restrict__ ws) {
    int qt = blockIdx.x, cc = blockIdx.y, b = blockIdx.z;
    int q = qt * 256 + threadIdx.x;
    if (q >= Ssz) return;
    const float* v0 = ws + OFF_V + (size_t)(b * 3 + 0) * Cch;
    const float* v1 = ws + OFF_V + (size_t)(b * 3 + 1) * Cch;
    const float* v2 = ws + OFF_V + (size_t)(b * 3 + 2) * Cch;
    float a0 = 0, a1 = 0, a2 = 0;
    int c0 = cc * 64;
    #pragma unroll 8
    for (int c = c0; c < c0 + 64; ++c) {
        float qv = query[((size_t)b * Cch + c) * Ssz + q];
        a0 += qv * v0[c]; a1 += qv * v1[c]; a2 += qv * v2[c];
    }
    float* dst = ws + OFF_DOT + (size_t)(b * 3) * Ssz + q;
    atomicAdd(&dst[0], a0);
    atomicAdd(&dst[Ssz], a1);
    atomicAdd(&dst[2 * Ssz], a2);
}

// ---------------- sim (bk 0..5) + APA-u role (bk 6..7) ----------------------
__global__ void __launch_bounds__(1024) k_sim(const float* __restrict__ text,
                                              const float* __restrict__ proto,
                                              const float* __restrict__ w_q,
                                              const float* __restrict__ w_bl,
                                              const float* __restrict__ w_k,
                                              float* __restrict__ ws) {
    int bkx = blockIdx.x;
    int tid = threadIdx.x;
    int lane = tid & 63, w = tid >> 6;

    if (bkx >= 6) {
        // ---- u role: u = w_k^T (w_bl^T (w_q^T [text;proto])) for b=bkx-6 ----
        int b = bkx - 6;
        __shared__ float4 p4[16][64];
        __shared__ float qxs[256], qws[256];
        const float4* wq4 = (const float4*)w_q;
        const float4* wbl4 = (const float4*)w_bl;
        const float4* wk4 = (const float4*)w_k;

        float4 acc = {0.f, 0.f, 0.f, 0.f};
        #pragma unroll
        for (int j = 0; j < 35; ++j) {
            int e = w + 16 * j;
            if (e < TDIM + HID) {
                float x = (e < TDIM) ? text[b * TDIM + e] : proto[b * HID + e - TDIM];
                float4 f = wq4[(size_t)e * 64 + lane];
                acc.x += x * f.x; acc.y += x * f.y; acc.z += x * f.z; acc.w += x * f.w;
            }
        }
        p4[w][lane] = acc;
        __syncthreads();
        if (tid < 256) {
            const float* pf = (const float*)p4;
            float s = 0.f;
            #pragma unroll
            for (int ww = 0; ww < 16; ++ww) s += pf[ww * 256 + tid];
            qxs[tid] = s;
        }
        __syncthreads();
        acc.x = acc.y = acc.z = acc.w = 0.f;
        #pragma unroll
        for (int j = 0; j < 16; ++j) {
            int e = w + 16 * j;
            float x = qxs[e];
            float4 f = wbl4[(size_t)e * 64 + lane];
            acc.x += x * f.x; acc.y += x * f.y; acc.z += x * f.z; acc.w += x * f.w;
        }
        p4[w][lane] = acc;
        __syncthreads();
        if (tid < 256) {
            const float* pf = (const float*)p4;
            float s = 0.f;
            #pragma unroll
            for (int ww = 0; ww < 16; ++ww) s += pf[ww * 256 + tid];
            qws[tid] = s;
        }
        __syncthreads();
        acc.x = acc.y = acc.z = acc.w = 0.f;
        #pragma unroll
        for (int j = 0; j < 16; ++j) {
            int e = w + 16 * j;
            float x = qws[e];
            float4 f = wk4[(size_t)e * 64 + lane];
            acc.x += x * f.x; acc.y += x * f.y; acc.z += x * f.z; acc.w += x * f.w;
        }
        p4[w][lane] = acc;
        __syncthreads();
        if (tid < 256) {
            const float* pf = (const float*)p4;
            float s = 0.f;
            #pragma unroll
            for (int ww = 0; ww < 16; ++ww) s += pf[ww * 256 + tid];
            ws[OFF_U + b * HID + tid] = s;
        }
        return;
    }

    // ---- sim role ----
    __shared__ float sA[66 * LPITCH];
    __shared__ float sB[66 * LPITCH];
    __shared__ float rmin[16], rmax[16];
    int bk = bkx; int b = bk / 3; int kt = bk % 3;

    const float* dp0 = ws + OFF_DOT + (size_t)(b * 3 + kt) * Ssz;
    for (int i = tid; i < 66 * LPITCH; i += 1024) {
        int r = i / LPITCH, col = i - r * LPITCH;
        int y = r - 3, x = col - 4;
        float s = 0.f;
        if (y >= 0 && y < Hh && x >= 0 && x < Hh) {
            s = dp0[y * Hh + x];
        }
        sA[i] = s;
    }
    __syncthreads();
    if (kt != 1) {
        for (int idx = tid; idx < 66 * 60; idx += 1024) {
            int r = idx / 60, x = idx - 60 * r;
            int base = r * LPITCH + 4 + x;
            if (kt == 0)
                sB[base] = sA[base - 2] + sA[base - 1] + sA[base] + sA[base + 1] + sA[base + 2];
            else
                sB[base] = sA[base - 3] + sA[base - 2] + sA[base - 1] + sA[base]
                         + sA[base + 1] + sA[base + 2] + sA[base + 3];
        }
    }
    __syncthreads();
    float norm = ((kt == 0) ? (1.f / 25.f) : (1.f / 7.f)) * (1.f / (float)Ssz);
    float vals[4];
    float vmin = INFINITY, vmax = -INFINITY;
    #pragma unroll
    for (int j = 0; j < 4; ++j) {
        int q = tid + j * 1024;
        if (q < Ssz) {
            int y = q / Hh, x = q - y * Hh;
            int base = (y + 3) * LPITCH + 4 + x;
            float s;
            if (kt == 0)
                s = sB[base - 2*LPITCH] + sB[base - LPITCH] + sB[base]
                  + sB[base + LPITCH] + sB[base + 2*LPITCH];
            else if (kt == 1)
                s = sA[base - 3*LPITCH] + sA[base - 2*LPITCH] + sA[base - LPITCH]
                  + sA[base] + sA[base + LPITCH] + sA[base + 2*LPITCH] + sA[base + 3*LPITCH];
            else
                s = sB[base];
            float val = s * norm;
            vals[j] = val;
            vmin = fminf(vmin, val); vmax = fmaxf(vmax, val);
        }
    }
    #pragma unroll
    for (int m = 32; m >= 1; m >>= 1) {
        vmin = fminf(vmin, __shfl_xor(vmin, m, 64));
        vmax = fmaxf(vmax, __shfl_xor(vmax, m, 64));
    }
    if (lane == 0) { rmin[w] = vmin; rmax[w] = vmax; }
    __syncthreads();
    float mn = rmin[0], mx = rmax[0];
    #pragma unroll
    for (int ww = 1; ww < 16; ++ww) {
        mn = fminf(mn, rmin[ww]); mx = fmaxf(mx, rmax[ww]);
    }
    float inv = 1.f / (mx - mn + EPSF);
    float* np = ws + OFF_NORM + (size_t)(b * 3 + kt) * Ssz;
    #pragma unroll
    for (int j = 0; j < 4; ++j) {
        int q = tid + j * 1024;
        if (q < Ssz) np[q] = (vals[j] - mn) * inv;
    }
}

// ---------------- score strips (st 0..28) + corr-final role (st 29) ---------
__global__ void __launch_bounds__(1024)
k_score(const float* __restrict__ kin, const float* __restrict__ weight,
        float* __restrict__ ws, float* __restrict__ out) {
    int st = blockIdx.x, b = blockIdx.y;
    int tid = threadIdx.x;

    if (st == 29) {
        // ---- corr final role: one block per b ----
        __shared__ float sF[Ssz];
        float wq3 = weight[b] * (1.f / 3.f);
        const float* n0 = ws + OFF_NORM + (size_t)(b * 3 + 0) * Ssz;
        const float* n1 = ws + OFF_NORM + (size_t)(b * 3 + 1) * Ssz;
        const float* n2 = ws + OFF_NORM + (size_t)(b * 3 + 2) * Ssz;
        #pragma unroll
        for (int j = 0; j < 4; ++j) {
            int q = tid + j * 1024;
            if (q < Ssz) {
                float s = n0[q] + n1[q] + n2[q];
                sF[q] = s;
                out[b * Ssz + q] = wq3 * s;
            }
        }
        __syncthreads();
        #pragma unroll
        for (int j = 0; j < 2; ++j) {
            int o = tid + j * 1024;
            if (o >= 1189) continue;
            int O, p, outi;
            if (o < 900)       { O = 30; p = o;        outi = 7200 + b * 900 + p; }
            else if (o < 1125) { O = 15; p = o - 900;  outi = 9000 + b * 225 + p; }
            else               { O = 8;  p = o - 1125; outi = 9450 + b * 64 + p; }
            int y = p / O, x = p - y * O;
            float sc = 59.f / (float)(O - 1);
            float py = y * sc, px = x * sc;
            int y0 = (int)floorf(py), x0 = (int)floorf(px);
            int y1 = min(y0 + 1, 59), x1 = min(x0 + 1, 59);
            float wy = py - y0, wx = px - x0;
            float v = sF[y0 * 60 + x0] * (1.f - wy) * (1.f - wx)
                    + sF[y1 * 60 + x0] * wy * (1.f - wx)
                    + sF[y0 * 60 + x1] * (1.f - wy) * wx
                    + sF[y1 * 60 + x1] * wy * wx;
            out[outi] = wq3 * v;
        }
        return;
    }

    // ---- score role: 128 s-values, 8-way i-split, LDS reduce ----
    __shared__ float us[HID];
    __shared__ float part[8][128];
    if (tid < HID) us[tid] = ws[OFF_U + b * HID + tid];
    __syncthreads();
    int sl = tid & 127, pt = tid >> 7;          // pt = 0..7
    int s = st * 128 + sl;
    float a = 0.f;
    if (s < Ssz) {
        const float* kb = kin + ((size_t)b * HID + pt * 32) * Ssz + s;
        const float* up = us + pt * 32;
        #pragma unroll
        for (int i = 0; i < 32; ++i) a += up[i] * kb[(size_t)i * Ssz];
    }
    part[pt][sl] = a;
    __syncthreads();
    if (tid < 128 && st * 128 + tid < Ssz) {
        float t = 0.f;
        #pragma unroll
        for (int p = 0; p < 8; ++p) t += part[p][tid];
        ws[OFF_SCORE + (size_t)b * Ssz + st * 128 + tid] = t;
    }
}

// ---------------- kbar[b,i] = softmax(score) . k[b,i,:]  (softmax fused) ----
__global__ void k_kbar(const float* __restrict__ kin, float* __restrict__ ws) {
    int i = blockIdx.x, b = blockIdx.y;
    int tid = threadIdx.x;
    int lane = tid & 63, w = tid >> 6;
    __shared__ float r1[4], r2[4];
    const float4* s4 = (const float4*)(ws + OFF_SCORE + (size_t)b * Ssz);
    float4 sv[4]; bool act[4];
    float mx = -INFINITY;
    #pragma unroll
    for (int j = 0; j < 4; ++j) {
        int idx = tid + 256 * j;
        act[j] = idx < 900;
        if (act[j]) {
            float4 v = s4[idx];
            sv[j] = v;
            mx = fmaxf(mx, fmaxf(fmaxf(v.x, v.y), fmaxf(v.z, v.w)));
        }
    }
    #pragma unroll
    for (int m = 32; m >= 1; m >>= 1) mx = fmaxf(mx, __shfl_xor(mx, m, 64));
    if (lane == 0) r1[w] = mx;
    __syncthreads();
    mx = fmaxf(fmaxf(r1[0], r1[1]), fmaxf(r1[2], r1[3]));
    __syncthreads();
    const float4* kr = (const float4*)(kin + ((size_t)b * HID + i) * Ssz);
    float se = 0.f, wsum = 0.f;
    #pragma unroll
    for (int j = 0; j < 4; ++j) {
        if (act[j]) {
            int idx = tid + 256 * j;
            float4 v = sv[j];
            float ex = expf(v.x - mx), ey = expf(v.y - mx);
            float ez = expf(v.z - mx), ew = expf(v.w - mx);
            se += ex + ey + ez + ew;
            float4 k4 = kr[idx];
            wsum += ex * k4.x + ey * k4.y + ez * k4.z + ew * k4.w;
        }
    }
    #pragma unroll
    for (int m = 32; m >= 1; m >>= 1) {
        se += __shfl_xor(se, m, 64);
        wsum += __shfl_xor(wsum, m, 64);
    }
    if (lane == 0) { r1[w] = se; r2[w] = wsum; }
    __syncthreads();
    if (tid == 0) {
        float seT = r1[0] + r1[1] + r1[2] + r1[3];
        float wsT = r2[0] + r2[1] + r2[2] + r2[3];
        ws[OFF_KBAR + b * HID + i] = wsT / seT;
    }
}

// ---------------- out = w_proj^T (w_k kbar) + b + proto ---------------------
__global__ void __launch_bounds__(1024, 1)
k_apa_out(const float* __restrict__ w_k, const float* __restrict__ w_proj,
          const float* __restrict__ b_proj, const float* __restrict__ proto,
          const float* __restrict__ ws, float* __restrict__ out) {
    int b = blockIdx.x;
    int tid = threadIdx.x;
    int lane = tid & 63, w = tid >> 6;
    __shared__ float4 kbs[64];
    __shared__ float o1s[256];
    __shared__ float4 p4[16][64];
    const float4* wk4 = (const float4*)w_k;
    const float4* wp4 = (const float4*)w_proj;

    if (tid < 64) kbs[tid] = ((const float4*)(ws + OFF_KBAR + b * HID))[tid];
    __syncthreads();

    float4 kb4 = kbs[lane];
    #pragma unroll
    for (int r = 0; r < 16; ++r) {
        int h = w + 16 * r;
        float4 f = wk4[(size_t)h * 64 + lane];
        float p = f.x * kb4.x + f.y * kb4.y + f.z * kb4.z + f.w * kb4.w;
        #pragma unroll
        for (int m = 32; m >= 1; m >>= 1) p += __shfl_xor(p, m, 64);
        if (lane == 0) o1s[h] = p;
    }
    __syncthreads();

    float4 acc = {0.f, 0.f, 0.f, 0.f};
    #pragma unroll
    for (int j = 0; j < 16; ++j) {
        int d = w + 16 * j;
        float x = o1s[d];
        float4 f = wp4[(size_t)d * 64 + lane];
        acc.x += x * f.x; acc.y += x * f.y; acc.z += x * f.z; acc.w += x * f.w;
    }
    p4[w][lane] = acc;
    __syncthreads();
    if (tid < 256) {
        const float* pf = (const float*)p4;
        float s = 0.f;
        #pragma unroll
        for (int ww = 0; ww < 16; ++ww) s += pf[ww * 256 + tid];
        out[9578 + b * HID + tid] = s + b_proj[tid] + proto[b * HID + tid];
    }
}

extern "C" void kernel_launch(void* const* d_in, const int* in_sizes, int n_in,
                              void* d_out, int out_size, void* d_ws, size_t ws_size,
                              hipStream_t stream) {
    const float* weight = (const float*)d_in[0];
    const float* query  = (const float*)d_in[1];
    const float* supp   = (const float*)d_in[2];
    const float* masks  = (const float*)d_in[3];
    const float* kin    = (const float*)d_in[4];
    const float* text   = (const float*)d_in[5];
    const float* proto  = (const float*)d_in[6];
    const float* w_q    = (const float*)d_in[7];
    const float* w_k    = (const float*)d_in[8];
    const float* w_bl   = (const float*)d_in[9];
    const float* w_proj = (const float*)d_in[10];
    const float* b_proj = (const float*)d_in[11];
    float* out = (float*)d_out;
    float* ws  = (float*)d_ws;

    // zero the two atomic accumulator planes (6*3600 SN2 + 6*3600 DOT)
    hipMemsetAsync(ws, 0, (size_t)(2 * 6 * Ssz) * sizeof(float), stream);

    k_pool_sn2<<<dim3(4, 128, 2), 256, 0, stream>>>(supp, masks, ws);
    k_wmap<<<dim3(4, 6), 1024, 0, stream>>>(masks, ws);
    k_v<<<dim3(256, 2), 256, 0, stream>>>(supp, ws);
    k_dot<<<dim3(15, 16, 2), 256, 0, stream>>>(query, ws);
    k_sim<<<8, 1024, 0, stream>>>(text, proto, w_q, w_bl, w_k, ws);
    k_score<<<dim3(30, 2), 1024, 0, stream>>>(kin, weight, ws, out);
    k_kbar<<<dim3(HID, 2), 256, 0, stream>>>(kin, ws);
    k_apa_out<<<Bsz, 1024, 0, stream>>>(w_k, w_proj, b_proj, proto, ws, out);
}